// Round 15
// baseline (14619.989 us; speedup 1.0000x reference)
//
#include <hip/hip_runtime.h>
#include <hip/hip_bf16.h>
#include <stdint.h>

// LSTM: S=1024, B=64, D=1024, H=1024. fp32 in/out, bf16 MFMA internally.
// out = [Yt (S*B*H) | hT (B*H) | cT (B*H)] fp32.
// R15: 4-chain batch interleave. 64 WGs x 256 thr; WG owns j0=wg*16..+16
// (weights w[8][4] in AGPRs, shared by all chains) and processes 4
// independent 16-row batch chains per step. Each chain has its own barrier;
// settle of chain c hides under chains c+1..c+3's work.

typedef __attribute__((ext_vector_type(8))) short bf16x8;
typedef __attribute__((ext_vector_type(4))) float f32x4;

__device__ __forceinline__ unsigned short f2bf(float f) {
    unsigned u = __builtin_bit_cast(unsigned, f);
    return (unsigned short)((u + 0x7fffu + ((u >> 16) & 1u)) >> 16);
}
__device__ __forceinline__ float fast_sigmoid(float x) {
    return __builtin_amdgcn_rcpf(1.f + __expf(-x));
}
__device__ __forceinline__ float fast_tanh(float x) {
    float xc = fminf(fmaxf(x, -9.f), 9.f);
    float e = __expf(2.f * xc);
    return (e - 1.f) * __builtin_amdgcn_rcpf(e + 1.f);
}

// ---------------- init: bias fusion + state zeroing ----------------
__global__ void init_kernel(const float* __restrict__ iiB, const float* __restrict__ hiB,
                            const float* __restrict__ ifB, const float* __restrict__ hfB,
                            const float* __restrict__ igB, const float* __restrict__ hgB,
                            const float* __restrict__ ioB, const float* __restrict__ hoB,
                            float* __restrict__ bias, unsigned short* __restrict__ hbuf0,
                            float* __restrict__ c_ws, unsigned int* __restrict__ bar) {
    int tid = blockIdx.x * 256 + threadIdx.x;   // grid 64 x 256 = 16384
    if (tid < 128) bar[tid] = 0u;               // chain counters at bar[c*32], c=0..3
    if (tid < 4096) {
        int g = tid >> 10, j = tid & 1023;
        const float* ib = (g == 0 ? iiB : g == 1 ? ifB : g == 2 ? igB : ioB);
        const float* hb = (g == 0 ? hiB : g == 1 ? hfB : g == 2 ? hgB : hoB);
        bias[tid] = ib[j] + hb[j];
    }
    for (int i = tid; i < 65536; i += 16384) {
        __hip_atomic_store(hbuf0 + i, (unsigned short)0, __ATOMIC_RELAXED, __HIP_MEMORY_SCOPE_AGENT);
        c_ws[i] = 0.f;
    }
}

// ---------------- weights -> bf16, gate-stacked n = g*1024 + j ----------------
__global__ void prep_weights(const float* __restrict__ iiW, const float* __restrict__ hiW,
                             const float* __restrict__ ifW, const float* __restrict__ hfW,
                             const float* __restrict__ igW, const float* __restrict__ hgW,
                             const float* __restrict__ ioW, const float* __restrict__ hoW,
                             unsigned short* __restrict__ Wx, unsigned short* __restrict__ Wh) {
    int n = blockIdx.x;               // 0..4095
    int g = n >> 10, j = n & 1023;
    const float* wx = (g == 0 ? iiW : g == 1 ? ifW : g == 2 ? igW : ioW) + (size_t)j * 1024;
    const float* wh = (g == 0 ? hiW : g == 1 ? hfW : g == 2 ? hgW : hoW) + (size_t)j * 1024;
    int k = threadIdx.x * 4;
    float4 a = *(const float4*)(wx + k);
    float4 b = *(const float4*)(wh + k);
    ushort4 ra = { f2bf(a.x), f2bf(a.y), f2bf(a.z), f2bf(a.w) };
    ushort4 rb = { f2bf(b.x), f2bf(b.y), f2bf(b.z), f2bf(b.w) };
    *(ushort4*)(Wx + (size_t)n * 1024 + k) = ra;
    *(ushort4*)(Wh + (size_t)n * 1024 + k) = rb;
}

// ---------------- Xproj GEMM: C[M][.] = A[M][1024] @ Wx^T + bias ----------------
// 128x128 tile, BK=32, 4 waves each 64x64 (4x4 of 16x16x32 bf16 MFMA).
// Output column PERMUTED: gate-stacked n (= g*1024+j) lands at column j*4+g.
__global__ __launch_bounds__(256, 2) void xproj_gemm(const float* __restrict__ A,
                                                     const unsigned short* __restrict__ Wx,
                                                     const float* __restrict__ bias,
                                                     float* __restrict__ C) {
    __shared__ __align__(16) unsigned short Asm[128 * 32];  // 8KB, XOR-swizzled slots
    __shared__ __align__(16) unsigned short Bsm[128 * 32];  // 8KB
    int tid = threadIdx.x;
    int lane = tid & 63, wv = tid >> 6;
    int l15 = lane & 15, l4 = lane >> 4;
    int wrow = wv >> 1, wcol = wv & 1;
    int bn0 = blockIdx.x * 128, bm0 = blockIdx.y * 128;
    f32x4 acc[4][4] = {};

    for (int kk = 0; kk < 32; ++kk) {
        int k0 = kk * 32;
        __syncthreads();
#pragma unroll
        for (int it = 0; it < 2; ++it) {
            int tau = it * 256 + tid;
            int row = tau >> 2, slot = tau & 3;
            const float* src = A + (size_t)(bm0 + row) * 1024 + k0 + slot * 8;
            float4 x0 = *(const float4*)src;
            float4 x1 = *(const float4*)(src + 4);
            bf16x8 pk;
            pk[0] = (short)f2bf(x0.x); pk[1] = (short)f2bf(x0.y);
            pk[2] = (short)f2bf(x0.z); pk[3] = (short)f2bf(x0.w);
            pk[4] = (short)f2bf(x1.x); pk[5] = (short)f2bf(x1.y);
            pk[6] = (short)f2bf(x1.z); pk[7] = (short)f2bf(x1.w);
            int dslot = slot ^ (row & 3);
            *(bf16x8*)((char*)Asm + row * 64 + dslot * 16) = pk;
        }
#pragma unroll
        for (int it = 0; it < 2; ++it) {
            int tau = it * 256 + tid;
            int row = tau >> 2, slot = tau & 3;
            int sslot = slot ^ (row & 3);
            const unsigned short* src = Wx + (size_t)(bn0 + row) * 1024 + k0 + sslot * 8;
            char* ldsb = (char*)Bsm + it * 4096 + wv * 1024;
            __builtin_amdgcn_global_load_lds((const __attribute__((address_space(1))) void*)src,
                                             (__attribute__((address_space(3))) void*)ldsb, 16, 0, 0);
        }
        __syncthreads();
        bf16x8 af[4], bfv[4];
#pragma unroll
        for (int i = 0; i < 4; ++i) {
            int rowa = wrow * 64 + i * 16 + l15;
            int sa = l4 ^ (rowa & 3);
            af[i] = *(const bf16x8*)((const char*)Asm + rowa * 64 + sa * 16);
            int rowb = wcol * 64 + i * 16 + l15;
            int sb = l4 ^ (rowb & 3);
            bfv[i] = *(const bf16x8*)((const char*)Bsm + rowb * 64 + sb * 16);
        }
#pragma unroll
        for (int i = 0; i < 4; ++i)
#pragma unroll
            for (int j = 0; j < 4; ++j)
                acc[i][j] = __builtin_amdgcn_mfma_f32_16x16x32_bf16(af[i], bfv[j], acc[i][j], 0, 0, 0);
    }
#pragma unroll
    for (int i = 0; i < 4; ++i) {
        int m = bm0 + wrow * 64 + i * 16 + l4 * 4;
#pragma unroll
        for (int j = 0; j < 4; ++j) {
            int n = bn0 + wcol * 64 + j * 16 + l15;
            int col = (n & 1023) * 4 + (n >> 10);
            float bs = bias[n];
#pragma unroll
            for (int r = 0; r < 4; ++r)
                C[(size_t)(m + r) * 4096 + col] = acc[i][j][r] + bs;
        }
    }
}

// ---------------- persistent recurrent kernel (one chunk of T steps) ----------------
// 64 WGs x 256 thr. WG wg owns j0 = wg*16..+16 (all 4 gates), weights K-split
// across 4 waves (kw = wv). Per step, processes 4 independent batch chains
// c=0..3 (rows c*16..+16), each with its own barrier bar[c*32] (pop 64).
// Pointwise: thread tid -> (prow = tid>>4, pj = tid&15), 1 output per chain.
__global__ __launch_bounds__(256, 1) void lstm_steps(const float* __restrict__ xproj,
                                                     unsigned short* __restrict__ hbuf,
                                                     float* __restrict__ c_ws,
                                                     const unsigned short* __restrict__ Wh,
                                                     unsigned int* __restrict__ bar,
                                                     float* __restrict__ out,
                                                     int t0, int T) {
    __shared__ float red[4160];   // 16.6KB: [s:64][65] padded stride
    int tid = threadIdx.x, lane = tid & 63, kw = tid >> 6;   // kw 0..3
    int l15 = lane & 15, l4 = lane >> 4;
    int wg = blockIdx.x;            // 0..63
    int j0 = wg * 16;
    int prow = tid >> 4, pj = tid & 15;   // pointwise mapping

    // weights: K slice [kw*256,+256) x 4 gates x 16 units (same as R6)
    bf16x8 w[8][4];
#pragma unroll
    for (int ks = 0; ks < 8; ++ks)
#pragma unroll
        for (int g = 0; g < 4; ++g) {
            int n = g * 1024 + j0 + l15;
            int k = kw * 256 + ks * 32 + l4 * 8;
            w[ks][g] = *(const bf16x8*)(Wh + (size_t)n * 1024 + k);
        }
#pragma unroll
    for (int ks = 0; ks < 8; ++ks)
#pragma unroll
        for (int g = 0; g < 4; ++g)
            asm volatile("" : "+a"(w[ks][g]));

    // persistent c state + step-0 xproj prefetch (per chain)
    float c_reg[4], yv[4];
    float4 xp_cur[4], xp_nxt[4];
#pragma unroll
    for (int c = 0; c < 4; ++c) {
        int b = c * 16 + prow;
        c_reg[c] = c_ws[(size_t)b * 1024 + j0 + pj];
        xp_cur[c] = *(const float4*)(xproj + (size_t)b * 4096 + (j0 + pj) * 4);
        yv[c] = 0.f;
    }

    for (int tl = 0; tl < T; ++tl) {
        int ts = t0 + tl;
        int par = ts & 1;
        const unsigned short* hb = hbuf + (size_t)par * 65536;
        unsigned short* hbn = hbuf + (size_t)(par ^ 1) * 65536;

#pragma unroll
        for (int c = 0; c < 4; ++c) {
            // ---- wait for chain c's h(ts) to be fully published ----
            if (tid == 0) {
                unsigned tgt = (unsigned)ts * 64u;
                while (__hip_atomic_load(bar + c * 32, __ATOMIC_RELAXED, __HIP_MEMORY_SCOPE_AGENT) < tgt)
                    __builtin_amdgcn_s_sleep(1);
            }
            __syncthreads();

            // ---- h fragments for chain c (16 rows, K-slice kw*256..+256) ----
            bf16x8 af[8];
            {
                const unsigned short* rp = hb + (size_t)(c * 16 + l15) * 1024 + kw * 256 + l4 * 8;
#pragma unroll
                for (int ks = 0; ks < 8; ++ks) {
                    unsigned long long* p = (unsigned long long*)(rp + ks * 32);
                    union { unsigned long long q[2]; bf16x8 v; } u;
                    u.q[0] = __hip_atomic_load(p,     __ATOMIC_RELAXED, __HIP_MEMORY_SCOPE_AGENT);
                    u.q[1] = __hip_atomic_load(p + 1, __ATOMIC_RELAXED, __HIP_MEMORY_SCOPE_AGENT);
                    af[ks] = u.v;
                }
            }

            f32x4 acc[4] = {};
#pragma unroll
            for (int ks = 0; ks < 8; ++ks)
#pragma unroll
                for (int g = 0; g < 4; ++g)
                    acc[g] = __builtin_amdgcn_mfma_f32_16x16x32_bf16(af[ks], w[ks][g], acc[g], 0, 0, 0);

            // cross-wave K reduction (padded stride 65: write banks 2-way free)
#pragma unroll
            for (int g = 0; g < 4; ++g)
#pragma unroll
                for (int r = 0; r < 4; ++r)
                    red[(kw * 16 + g * 4 + r) * 65 + lane] = acc[g][r];
            __syncthreads();

            // pointwise: one output (b = c*16+prow, j = j0+pj) per thread
            {
                int b = c * 16 + prow;
                int slot = (prow >> 2) * 16 + pj;
                int rr = prow & 3;
                const float* xpf = (const float*)&xp_cur[c];
                float pre[4];
#pragma unroll
                for (int g = 0; g < 4; ++g)
                    pre[g] = red[(0 * 16 + g * 4 + rr) * 65 + slot] +
                             red[(1 * 16 + g * 4 + rr) * 65 + slot] +
                             red[(2 * 16 + g * 4 + rr) * 65 + slot] +
                             red[(3 * 16 + g * 4 + rr) * 65 + slot] + xpf[g];
                float I = fast_sigmoid(pre[0]);
                float F = fast_sigmoid(pre[1]);
                float G = fast_tanh(pre[2]);
                float O = fast_sigmoid(pre[3]);
                float cc = F * c_reg[c] + I * G;
                c_reg[c] = cc;
                float y = O * fast_tanh(cc);
                yv[c] = y;
                __hip_atomic_store(hbn + (size_t)b * 1024 + j0 + pj, f2bf(y),
                                   __ATOMIC_RELAXED, __HIP_MEMORY_SCOPE_AGENT);
            }

            // drain h stores (L3 ack), then signal chain c complete
            __syncthreads();
            if (tid == 0)
                __hip_atomic_fetch_add(bar + c * 32, 1u, __ATOMIC_RELAXED, __HIP_MEMORY_SCOPE_AGENT);

            // post-arrive: out store + next-step xproj prefetch for chain c.
            // These drain at the NEXT chain's syncs, off the critical path.
            {
                int b = c * 16 + prow;
                out[(size_t)(ts * 64 + b) * 1024 + j0 + pj] = yv[c];
                int tln = (tl + 1 < T) ? tl + 1 : tl;
                xp_nxt[c] = *(const float4*)(xproj + (size_t)(tln * 64 + b) * 4096 + (j0 + pj) * 4);
            }
        }
#pragma unroll
        for (int c = 0; c < 4; ++c) xp_cur[c] = xp_nxt[c];
    }

    // epilogue: hT/cT + persist c
#pragma unroll
    for (int c = 0; c < 4; ++c) {
        int b = c * 16 + prow;
        if (t0 + T == 1024) {
            out[67108864u + (size_t)b * 1024 + j0 + pj] = yv[c];           // hT
            out[67108864u + 65536u + (size_t)b * 1024 + j0 + pj] = c_reg[c]; // cT
        }
        c_ws[(size_t)b * 1024 + j0 + pj] = c_reg[c];
    }
}

extern "C" void kernel_launch(void* const* d_in, const int* in_sizes, int n_in,
                              void* d_out, int out_size, void* d_ws, size_t ws_size,
                              hipStream_t stream) {
    (void)in_sizes; (void)n_in; (void)out_size;
    const float* Xt = (const float*)d_in[0];
    const float* W[8]; for (int i = 0; i < 8; ++i) W[i] = (const float*)d_in[1 + i];
    const float* Bv[8]; for (int i = 0; i < 8; ++i) Bv[i] = (const float*)d_in[9 + i];
    float* out = (float*)d_out;
    uint8_t* ws = (uint8_t*)d_ws;

    unsigned int*  bar   = (unsigned int*)(ws + 0);           // 128 uints (4 chain ctrs)
    float*         bias  = (float*)(ws + 512);
    unsigned short* hbuf = (unsigned short*)(ws + 16896);     // [2][64][1024] bf16
    float*         c_ws  = (float*)(ws + 279040);             // [64][1024] fp32
    unsigned short* Wx   = (unsigned short*)(ws + 541184);    // [4096][1024] bf16
    unsigned short* Wh   = (unsigned short*)(ws + 8929792);   // [4096][1024] bf16
    float*         xproj = (float*)(ws + 17318400);           // [T*64][4096] fp32

    size_t avail = ws_size > 17318400 ? ws_size - 17318400 : 0;
    int T = 4;
    for (int t = 1024; t >= 4; t >>= 1)
        if ((size_t)t * 1048576ull <= avail) { T = t; break; }

    init_kernel<<<64, 256, 0, stream>>>(Bv[0], Bv[1], Bv[2], Bv[3], Bv[4], Bv[5], Bv[6], Bv[7],
                                        bias, hbuf, c_ws, bar);
    prep_weights<<<4096, 256, 0, stream>>>(W[0], W[1], W[2], W[3], W[4], W[5], W[6], W[7], Wx, Wh);

    int nch = 1024 / T;
    for (int c = 0; c < nch; ++c) {
        xproj_gemm<<<dim3(32, T / 2), 256, 0, stream>>>(Xt + (size_t)c * T * 65536, Wx, bias, xproj);
        lstm_steps<<<64, 256, 0, stream>>>(xproj, hbuf, c_ws, Wh, bar, out, c * T, T);
    }
}